// Round 1
// baseline (96.057 us; speedup 1.0000x reference)
//
#include <hip/hip_runtime.h>
#include <math.h>

#define NF 512
#define HD 128
#define NB 512
#define NPAIRS 130816

// ws layout (float units): M[512*512] at 0, fm_acc[512] at WS_ACC
#define WS_ACC 262144

// Swizzled LDS layout for x^T tile: row j (512 rows), 8 floats (r=0..7) per row,
// stored as two float4 halves. XOR spreads concurrent j's across banks:
//   byte = j*32 + h*16;  byte ^= (j & 0x60);  byte ^= (j & 0x80) >> 3;
// -> concurrent 8 j2-rows per wave hit >=4 distinct 4-bank groups (2-way, free).
__device__ __forceinline__ int xswz(int j, int h) {
  int a = (j << 5) + (h << 4);
  a ^= (j & 0x60);
  a ^= ((j & 0x80) >> 3);
  return a >> 2;  // float index
}

// K1: M[j1][j2] = (j2>j1) ? dot(fm_w[j1],fm_w[j2]) * wo[triu_idx] : 0
//     block 1024 zeroes the fm accumulator.
__global__ __launch_bounds__(256) void k_build(
    const float* __restrict__ fmw, const float* __restrict__ wo,
    float* __restrict__ ws) {
  if (blockIdx.x == 1024) {
    int t = threadIdx.x;
    ws[WS_ACC + t] = 0.f;
    ws[WS_ACC + 256 + t] = 0.f;
    return;
  }
  int t = blockIdx.x * 256 + threadIdx.x;
  int j1 = t >> 9, j2 = t & 511;
  const float4* fw = (const float4*)fmw;
  float4 a = fw[j1], b = fw[j2];
  float dot = a.x * b.x + a.y * b.y + a.z * b.z + a.w * b.w;
  float m = 0.f;
  if (j2 > j1) {
    int idx = j1 * (1023 - j1) / 2 + (j2 - j1 - 1);  // triu(k=1) row-major
    m = dot * wo[idx];
  }
  ws[t] = m;
}

// K3: fm_acc[b] += x[b,:]^T M x[b,:]  (quadratic form, M upper-triangular)
// grid 512 = 64 batch-groups (8 rows) x 8 j1-chunks (64 rows each).
// thread: j1g = tid&7 -> 8 j1 rows; j2s = tid>>3 -> 16 j2 columns.
// Register tile: tmp[8 rows][8 batch] accumulated over j2, then folded with x[b,j1].
__global__ __launch_bounds__(256, 2) void k_fm(
    const float* __restrict__ x, float* __restrict__ ws) {
  __shared__ float xt[4096];   // swizzled x^T tile, 16KB
  __shared__ float red[4][8];
  const int tid = threadIdx.x;
  const int bg = blockIdx.x >> 3;
  const int jc = blockIdx.x & 7;
  const int b0 = bg * 8;

  // stage 8 x-rows, transposed (coalesced global reads per r)
  #pragma unroll
  for (int half = 0; half < 2; ++half) {
    int j = tid + half * 256;
    float xr[8];
    #pragma unroll
    for (int r = 0; r < 8; ++r) xr[r] = x[(b0 + r) * NF + j];
    *(float4*)&xt[xswz(j, 0)] = make_float4(xr[0], xr[1], xr[2], xr[3]);
    *(float4*)&xt[xswz(j, 1)] = make_float4(xr[4], xr[5], xr[6], xr[7]);
  }
  __syncthreads();

  const int j1g = tid & 7;
  const int j2s = tid >> 3;
  const int j1base = jc * 64 + j1g * 8;
  const int j2base = j2s * 16;

  float tmp[8][8];
  #pragma unroll
  for (int i = 0; i < 8; ++i)
    #pragma unroll
    for (int r = 0; r < 8; ++r) tmp[i][r] = 0.f;

  #pragma unroll
  for (int c = 0; c < 4; ++c) {
    float xv[4][8];
    #pragma unroll
    for (int e = 0; e < 4; ++e) {
      int j2 = j2base + c * 4 + e;
      float4 lo = *(const float4*)&xt[xswz(j2, 0)];
      float4 hi = *(const float4*)&xt[xswz(j2, 1)];
      xv[e][0] = lo.x; xv[e][1] = lo.y; xv[e][2] = lo.z; xv[e][3] = lo.w;
      xv[e][4] = hi.x; xv[e][5] = hi.y; xv[e][6] = hi.z; xv[e][7] = hi.w;
    }
    #pragma unroll
    for (int i = 0; i < 8; ++i) {
      const float4 m4 = *(const float4*)&ws[(j1base + i) * NF + j2base + c * 4];
      float mm[4] = {m4.x, m4.y, m4.z, m4.w};
      #pragma unroll
      for (int e = 0; e < 4; ++e)
        #pragma unroll
        for (int r = 0; r < 8; ++r)
          tmp[i][r] += mm[e] * xv[e][r];  // 256 FMA per chunk
    }
  }

  // fold: acc[r] += tmp[i][r] * x[b0+r, j1base+i]
  float acc[8];
  #pragma unroll
  for (int r = 0; r < 8; ++r) acc[r] = 0.f;
  #pragma unroll
  for (int i = 0; i < 8; ++i) {
    int j1 = j1base + i;
    float4 lo = *(const float4*)&xt[xswz(j1, 0)];
    float4 hi = *(const float4*)&xt[xswz(j1, 1)];
    float xj[8] = {lo.x, lo.y, lo.z, lo.w, hi.x, hi.y, hi.z, hi.w};
    #pragma unroll
    for (int r = 0; r < 8; ++r) acc[r] += tmp[i][r] * xj[r];
  }

  // block reduce -> one atomicAdd per batch row
  #pragma unroll
  for (int off = 32; off > 0; off >>= 1)
    #pragma unroll
    for (int r = 0; r < 8; ++r) acc[r] += __shfl_down(acc[r], off, 64);
  const int wave = tid >> 6, lane = tid & 63;
  if (lane == 0)
    #pragma unroll
    for (int r = 0; r < 8; ++r) red[wave][r] = acc[r];
  __syncthreads();
  if (tid < 8) {
    float s = red[0][tid] + red[1][tid] + red[2][tid] + red[3][tid];
    atomicAdd(&ws[WS_ACC + b0 + tid], s);
  }
}

// K2: deep MLP (relu(x@W1+b1) -> relu(@W2+b2)) fused with final combine+sigmoid.
// grid 256 blocks x 2 batch rows; thread: h = tid&127, jh = tid>>7 splits inner dim.
__global__ __launch_bounds__(256) void k_deep(
    const float* __restrict__ x, const float* __restrict__ w1,
    const float* __restrict__ b1, const float* __restrict__ w2,
    const float* __restrict__ b2v, const float* __restrict__ wo,
    const float* __restrict__ bo, const float* __restrict__ ws,
    float* __restrict__ out) {
  __shared__ float xs[2][512];
  __shared__ float p1[2][2][128];
  __shared__ float h1[2][128];
  __shared__ float p2[2][2][128];
  __shared__ float wpart[4];
  const int tid = threadIdx.x;
  const int b0 = blockIdx.x * 2;
  const int h = tid & 127, jh = tid >> 7;

  #pragma unroll
  for (int r = 0; r < 2; ++r) {
    xs[r][tid] = x[(b0 + r) * NF + tid];
    xs[r][tid + 256] = x[(b0 + r) * NF + tid + 256];
  }
  __syncthreads();

  float a0 = 0.f, a1 = 0.f;
  const float* w1p = w1 + h;
  for (int j = 0; j < 256; ++j) {
    int jj = jh * 256 + j;
    float w = w1p[jj * 128];        // coalesced across h
    a0 += xs[0][jj] * w;            // LDS broadcast
    a1 += xs[1][jj] * w;
  }
  p1[jh][0][h] = a0;
  p1[jh][1][h] = a1;
  __syncthreads();
  {
    int r = jh;  // 256 threads cover 2 rows x 128 h
    float v = p1[0][r][h] + p1[1][r][h] + b1[h];
    h1[r][h] = v > 0.f ? v : 0.f;
  }
  __syncthreads();

  float c0 = 0.f, c1 = 0.f;
  const float* w2p = w2 + h;
  for (int k = 0; k < 64; ++k) {
    int kk = jh * 64 + k;
    float w = w2p[kk * 128];
    c0 += h1[0][kk] * w;
    c1 += h1[1][kk] * w;
  }
  p2[jh][0][h] = c0;
  p2[jh][1][h] = c1;
  __syncthreads();

  float val;
  {
    int r = jh;
    float v = p2[0][r][h] + p2[1][r][h] + b2v[h];
    v = v > 0.f ? v : 0.f;
    val = v * wo[NPAIRS + h];
  }
  #pragma unroll
  for (int off = 32; off > 0; off >>= 1) val += __shfl_down(val, off, 64);
  const int wave = tid >> 6, lane = tid & 63;
  if (lane == 0) wpart[wave] = val;  // waves 0,1 -> r=0; waves 2,3 -> r=1
  __syncthreads();
  if (tid < 2) {
    float z = wpart[tid * 2] + wpart[tid * 2 + 1] + bo[0] + ws[WS_ACC + b0 + tid];
    out[b0 + tid] = 1.f / (1.f + expf(-z));
  }
}

extern "C" void kernel_launch(void* const* d_in, const int* in_sizes, int n_in,
                              void* d_out, int out_size, void* d_ws, size_t ws_size,
                              hipStream_t stream) {
  const float* x   = (const float*)d_in[0];
  const float* fmw = (const float*)d_in[1];
  const float* w1  = (const float*)d_in[2];
  const float* b1  = (const float*)d_in[3];
  const float* w2  = (const float*)d_in[4];
  const float* b2  = (const float*)d_in[5];
  const float* wo  = (const float*)d_in[6];
  const float* bo  = (const float*)d_in[7];
  float* out = (float*)d_out;
  float* ws  = (float*)d_ws;

  hipLaunchKernelGGL(k_build, dim3(1025), dim3(256), 0, stream, fmw, wo, ws);
  hipLaunchKernelGGL(k_fm,    dim3(512),  dim3(256), 0, stream, x, ws);
  hipLaunchKernelGGL(k_deep,  dim3(256),  dim3(256), 0, stream, x, w1, b1, w2, b2,
                     wo, bo, ws, out);
}

// Round 4
// 93.347 us; speedup vs baseline: 1.0290x; 1.0290x over previous
//
#include <hip/hip_runtime.h>
#include <math.h>

#define NF 512
#define HD 128
#define NB 512
#define NPAIRS 130816

// ws layout (float units):
//   M[512*512]            at 0
//   fm partials [32][512] at WS_ACC
//   W1^T [128][512]       at WS_W1T
//   W2^T [128][128]       at WS_W2T
#define WS_ACC 262144
#define WS_W1T 278528
#define WS_W2T 344064

// K1: build M, W1^T, W2^T. 1184 blocks.
//   blocks [0,1024):    M[j1][j2] = (j2>j1) ? dot(fm_w[j1],fm_w[j2])*wo[triu] : 0
//   blocks [1024,1152): W1^T (128 blocks x 512 elems)
//   blocks [1152,1184): W2^T (32 blocks x 512 elems)
__global__ __launch_bounds__(256) void k_build(
    const float* __restrict__ fmw, const float* __restrict__ wo,
    const float* __restrict__ w1, const float* __restrict__ w2,
    float* __restrict__ ws) {
  const int bid = blockIdx.x;
  if (bid < 1024) {
    int t = bid * 256 + threadIdx.x;
    int j1 = t >> 9, j2 = t & 511;
    const float4* fw = (const float4*)fmw;
    float4 a = fw[j1], b = fw[j2];
    float dot = a.x * b.x + a.y * b.y + a.z * b.z + a.w * b.w;
    float m = 0.f;
    if (j2 > j1) {
      int idx = j1 * (1023 - j1) / 2 + (j2 - j1 - 1);  // triu(k=1) row-major
      m = dot * wo[idx];
    }
    ws[t] = m;
  } else if (bid < 1152) {
    int e = (bid - 1024) * 512 + threadIdx.x;
#pragma unroll
    for (int u = 0; u < 2; ++u, e += 256) {
      int k = e >> 7, h = e & 127;
      ws[WS_W1T + h * 512 + k] = w1[e];  // read coalesced, write scattered (tiny)
    }
  } else {
    int e = (bid - 1152) * 512 + threadIdx.x;
#pragma unroll
    for (int u = 0; u < 2; ++u, e += 256) {
      int k = e >> 7, h = e & 127;
      ws[WS_W2T + h * 128 + k] = w2[e];
    }
  }
}

// K2: fm partial[jc][b] = sum over j1 in chunk jc of x[b,j1] * (M[j1,:] . x[b,:])
// grid 2048 = 64 batch-groups (8 rows) x 32 j1-chunks (16 rows).
// Wave wv owns 4 j1 rows; lane owns one float4 of j2 per iter (contiguous 1KB/wave).
__global__ __launch_bounds__(256) void k_fm(
    const float* __restrict__ x, float* __restrict__ ws) {
  const int tid = threadIdx.x;
  const int bg = blockIdx.x >> 5;   // 64 batch groups
  const int jc = blockIdx.x & 31;   // 32 j1 chunks
  const int b0 = bg * 8;
  const int lane = tid & 63;
  const int wv = tid >> 6;
  const int j1base = jc * 16 + wv * 4;
  const float4* x4 = (const float4*)x;
  const float4* m4 = (const float4*)ws;

  float tmp[4][8];
#pragma unroll
  for (int i = 0; i < 4; ++i)
#pragma unroll
    for (int r = 0; r < 8; ++r) tmp[i][r] = 0.f;

#pragma unroll
  for (int it = 0; it < 2; ++it) {
    const int j2q = lane + it * 64;  // float4 index into a 512-float row
    float4 xq[8];
#pragma unroll
    for (int r = 0; r < 8; ++r) xq[r] = x4[(b0 + r) * 128 + j2q];
    float4 mm[4];
#pragma unroll
    for (int i = 0; i < 4; ++i) mm[i] = m4[(j1base + i) * 128 + j2q];
#pragma unroll
    for (int i = 0; i < 4; ++i)
#pragma unroll
      for (int r = 0; r < 8; ++r)
        tmp[i][r] += mm[i].x * xq[r].x + mm[i].y * xq[r].y +
                     mm[i].z * xq[r].z + mm[i].w * xq[r].w;
  }

  // fold with x[b, j1] (wave-uniform addresses -> broadcast loads)
  float acc[8];
#pragma unroll
  for (int r = 0; r < 8; ++r) acc[r] = 0.f;
#pragma unroll
  for (int i = 0; i < 4; ++i)
#pragma unroll
    for (int r = 0; r < 8; ++r)
      acc[r] += tmp[i][r] * x[(b0 + r) * NF + j1base + i];

  // reduce j2 partitions across the wave
#pragma unroll
  for (int off = 32; off > 0; off >>= 1)
#pragma unroll
    for (int r = 0; r < 8; ++r) acc[r] += __shfl_down(acc[r], off, 64);

  __shared__ float red[4][8];
  if (lane == 0)
#pragma unroll
    for (int r = 0; r < 8; ++r) red[wv][r] = acc[r];
  __syncthreads();
  if (tid < 8)
    ws[WS_ACC + jc * 512 + b0 + tid] =
        red[0][tid] + red[1][tid] + red[2][tid] + red[3][tid];
}

// K3: deep MLP + combine + sigmoid. 256 blocks x 512 threads, 2 batch rows/block.
// K-dim split 4 ways (part = tid>>7); W1^T/W2^T give float4 k-loops.
__global__ __launch_bounds__(512) void k_deep(
    const float* __restrict__ x, const float* __restrict__ b1,
    const float* __restrict__ b2, const float* __restrict__ wo,
    const float* __restrict__ bo, const float* __restrict__ ws,
    float* __restrict__ out) {
  __shared__ float xs[1024];
  __shared__ float p1[4][2][128];
  __shared__ float h1[2][128];
  __shared__ float p2[4][2][128];
  __shared__ float prod[2][128];
  const int tid = threadIdx.x;
  const int b0 = blockIdx.x * 2;

  xs[tid] = x[b0 * NF + tid];
  xs[tid + 512] = x[b0 * NF + 512 + tid];
  __syncthreads();

  const int h = tid & 127, part = tid >> 7;
  const float4* w1t4 = (const float4*)(ws + WS_W1T);
  const float4* xs4 = (const float4*)xs;

  float a0 = 0.f, a1 = 0.f;
#pragma unroll
  for (int q = 0; q < 32; ++q) {
    float4 w = w1t4[h * 128 + part * 32 + q];
    float4 v0 = xs4[part * 32 + q];          // wave-uniform -> LDS broadcast
    float4 v1 = xs4[128 + part * 32 + q];
    a0 += w.x * v0.x + w.y * v0.y + w.z * v0.z + w.w * v0.w;
    a1 += w.x * v1.x + w.y * v1.y + w.z * v1.z + w.w * v1.w;
  }
  p1[part][0][h] = a0;
  p1[part][1][h] = a1;
  __syncthreads();
  if (tid < 256) {
    int r = tid >> 7, hh = tid & 127;
    float v = p1[0][r][hh] + p1[1][r][hh] + p1[2][r][hh] + p1[3][r][hh] + b1[hh];
    h1[r][hh] = fmaxf(v, 0.f);
  }
  __syncthreads();

  const float4* w2t4 = (const float4*)(ws + WS_W2T);
  const float4* h14 = (const float4*)h1;
  float c0 = 0.f, c1 = 0.f;
#pragma unroll
  for (int q = 0; q < 8; ++q) {
    float4 w = w2t4[h * 32 + part * 8 + q];
    float4 y0 = h14[part * 8 + q];
    float4 y1 = h14[32 + part * 8 + q];
    c0 += w.x * y0.x + w.y * y0.y + w.z * y0.z + w.w * y0.w;
    c1 += w.x * y1.x + w.y * y1.y + w.z * y1.z + w.w * y1.w;
  }
  p2[part][0][h] = c0;
  p2[part][1][h] = c1;
  __syncthreads();
  if (tid < 256) {
    int r = tid >> 7, hh = tid & 127;
    float v = p2[0][r][hh] + p2[1][r][hh] + p2[2][r][hh] + p2[3][r][hh] + b2[hh];
    v = fmaxf(v, 0.f);
    prod[r][hh] = v * wo[NPAIRS + hh];
  }
  __syncthreads();

  if (tid < 128) {
    int r = tid >> 6, lane = tid & 63;
    float s = prod[r][lane] + prod[r][lane + 64];
    if (lane < 32) s += ws[WS_ACC + lane * 512 + b0 + r];  // fold fm partials
#pragma unroll
    for (int off = 32; off > 0; off >>= 1) s += __shfl_down(s, off, 64);
    if (lane == 0) out[b0 + r] = 1.f / (1.f + expf(-(s + bo[0])));
  }
}

extern "C" void kernel_launch(void* const* d_in, const int* in_sizes, int n_in,
                              void* d_out, int out_size, void* d_ws, size_t ws_size,
                              hipStream_t stream) {
  const float* x   = (const float*)d_in[0];
  const float* fmw = (const float*)d_in[1];
  const float* w1  = (const float*)d_in[2];
  const float* b1  = (const float*)d_in[3];
  const float* w2  = (const float*)d_in[4];
  const float* b2  = (const float*)d_in[5];
  const float* wo  = (const float*)d_in[6];
  const float* bo  = (const float*)d_in[7];
  float* out = (float*)d_out;
  float* ws  = (float*)d_ws;

  hipLaunchKernelGGL(k_build, dim3(1184), dim3(256), 0, stream, fmw, wo, w1, w2, ws);
  hipLaunchKernelGGL(k_fm,    dim3(2048), dim3(256), 0, stream, x, ws);
  hipLaunchKernelGGL(k_deep,  dim3(256),  dim3(512), 0, stream, x, b1, b2, wo, bo,
                     ws, out);
}

// Round 6
// 92.325 us; speedup vs baseline: 1.0404x; 1.0111x over previous
//
#include <hip/hip_runtime.h>
#include <math.h>

#define NF 512
#define HD 128
#define NB 512
#define NPAIRS 130816

// ws layout (float units):
//   M[512*512]            at 0
//   fm partials [32][512] at WS_ACC
//   W1^T [128][512]       at WS_W1T
//   W2^T [128][128]       at WS_W2T
#define WS_ACC 262144
#define WS_W1T 278528
#define WS_W2T 344064

// K1: build M, W1^T, W2^T. 1184 blocks.
//   blocks [0,1024):    M[j1][j2] = (j2>j1) ? dot(fm_w[j1],fm_w[j2])*wo[triu] : 0
//   blocks [1024,1152): W1^T (128 blocks x 512 elems)
//   blocks [1152,1184): W2^T (32 blocks x 512 elems)
__global__ __launch_bounds__(256) void k_build(
    const float* __restrict__ fmw, const float* __restrict__ wo,
    const float* __restrict__ w1, const float* __restrict__ w2,
    float* __restrict__ ws) {
  const int bid = blockIdx.x;
  if (bid < 1024) {
    int t = bid * 256 + threadIdx.x;
    int j1 = t >> 9, j2 = t & 511;
    const float4* fw = (const float4*)fmw;
    float4 a = fw[j1], b = fw[j2];
    float dot = a.x * b.x + a.y * b.y + a.z * b.z + a.w * b.w;
    float m = 0.f;
    if (j2 > j1) {
      int idx = j1 * (1023 - j1) / 2 + (j2 - j1 - 1);  // triu(k=1) row-major
      m = dot * wo[idx];
    }
    ws[t] = m;
  } else if (bid < 1152) {
    int e = (bid - 1024) * 512 + threadIdx.x;
#pragma unroll
    for (int u = 0; u < 2; ++u, e += 256) {
      int k = e >> 7, h = e & 127;
      ws[WS_W1T + h * 512 + k] = w1[e];  // read coalesced, write scattered (tiny)
    }
  } else {
    int e = (bid - 1152) * 512 + threadIdx.x;
#pragma unroll
    for (int u = 0; u < 2; ++u, e += 256) {
      int k = e >> 7, h = e & 127;
      ws[WS_W2T + h * 128 + k] = w2[e];
    }
  }
}

// K2: fm partial[jc][b] = sum over j1 in chunk jc of x[b,j1] * (M[j1,:] . x[b,:])
// grid 2048 = 64 batch-groups (8 rows) x 32 j1-chunks (16 rows).
// Wave wv owns 4 j1 rows; lane owns one float4 of j2 per iter (contiguous 1KB/wave).
// TRIANGLE SKIP: M[j1][j2]==0 for j2 <= j1, so chunk jc only scans j2 >= jc*16
// (in-band zeros are read harmlessly). Halves average M/x traffic and FMA count;
// heavy jc=0 blocks interleave across CUs (bid = bg*32 + jc).
__global__ __launch_bounds__(256) void k_fm(
    const float* __restrict__ x, float* __restrict__ ws) {
  const int tid = threadIdx.x;
  const int bg = blockIdx.x >> 5;   // 64 batch groups
  const int jc = blockIdx.x & 31;   // 32 j1 chunks
  const int b0 = bg * 8;
  const int lane = tid & 63;
  const int wv = tid >> 6;
  const int j1base = jc * 16 + wv * 4;
  const float4* x4 = (const float4*)x;
  const float4* m4 = (const float4*)ws;

  float tmp[4][8];
#pragma unroll
  for (int i = 0; i < 4; ++i)
#pragma unroll
    for (int r = 0; r < 8; ++r) tmp[i][r] = 0.f;

  for (int j2q = jc * 4 + lane; j2q < 128; j2q += 64) {
    float4 xq[8];
#pragma unroll
    for (int r = 0; r < 8; ++r) xq[r] = x4[(b0 + r) * 128 + j2q];
    float4 mm[4];
#pragma unroll
    for (int i = 0; i < 4; ++i) mm[i] = m4[(j1base + i) * 128 + j2q];
#pragma unroll
    for (int i = 0; i < 4; ++i)
#pragma unroll
      for (int r = 0; r < 8; ++r)
        tmp[i][r] += mm[i].x * xq[r].x + mm[i].y * xq[r].y +
                     mm[i].z * xq[r].z + mm[i].w * xq[r].w;
  }

  // fold with x[b, j1] (wave-uniform addresses -> broadcast loads)
  float acc[8];
#pragma unroll
  for (int r = 0; r < 8; ++r) acc[r] = 0.f;
#pragma unroll
  for (int i = 0; i < 4; ++i)
#pragma unroll
    for (int r = 0; r < 8; ++r)
      acc[r] += tmp[i][r] * x[(b0 + r) * NF + j1base + i];

  // reduce j2 partitions across the wave
#pragma unroll
  for (int off = 32; off > 0; off >>= 1)
#pragma unroll
    for (int r = 0; r < 8; ++r) acc[r] += __shfl_down(acc[r], off, 64);

  __shared__ float red[4][8];
  if (lane == 0)
#pragma unroll
    for (int r = 0; r < 8; ++r) red[wv][r] = acc[r];
  __syncthreads();
  if (tid < 8)
    ws[WS_ACC + jc * 512 + b0 + tid] =
        red[0][tid] + red[1][tid] + red[2][tid] + red[3][tid];
}

// K3: deep MLP + combine + sigmoid. 256 blocks x 512 threads, 2 batch rows/block.
// K-dim split 4 ways (part = tid>>7); W1^T/W2^T give float4 k-loops.
__global__ __launch_bounds__(512) void k_deep(
    const float* __restrict__ x, const float* __restrict__ b1,
    const float* __restrict__ b2, const float* __restrict__ wo,
    const float* __restrict__ bo, const float* __restrict__ ws,
    float* __restrict__ out) {
  __shared__ float xs[1024];
  __shared__ float p1[4][2][128];
  __shared__ float h1[2][128];
  __shared__ float p2[4][2][128];
  __shared__ float prod[2][128];
  const int tid = threadIdx.x;
  const int b0 = blockIdx.x * 2;

  xs[tid] = x[b0 * NF + tid];
  xs[tid + 512] = x[b0 * NF + 512 + tid];
  __syncthreads();

  const int h = tid & 127, part = tid >> 7;
  const float4* w1t4 = (const float4*)(ws + WS_W1T);
  const float4* xs4 = (const float4*)xs;

  float a0 = 0.f, a1 = 0.f;
#pragma unroll
  for (int q = 0; q < 32; ++q) {
    float4 w = w1t4[h * 128 + part * 32 + q];
    float4 v0 = xs4[part * 32 + q];          // wave-uniform -> LDS broadcast
    float4 v1 = xs4[128 + part * 32 + q];
    a0 += w.x * v0.x + w.y * v0.y + w.z * v0.z + w.w * v0.w;
    a1 += w.x * v1.x + w.y * v1.y + w.z * v1.z + w.w * v1.w;
  }
  p1[part][0][h] = a0;
  p1[part][1][h] = a1;
  __syncthreads();
  if (tid < 256) {
    int r = tid >> 7, hh = tid & 127;
    float v = p1[0][r][hh] + p1[1][r][hh] + p1[2][r][hh] + p1[3][r][hh] + b1[hh];
    h1[r][hh] = fmaxf(v, 0.f);
  }
  __syncthreads();

  const float4* w2t4 = (const float4*)(ws + WS_W2T);
  const float4* h14 = (const float4*)h1;
  float c0 = 0.f, c1 = 0.f;
#pragma unroll
  for (int q = 0; q < 8; ++q) {
    float4 w = w2t4[h * 32 + part * 8 + q];
    float4 y0 = h14[part * 8 + q];
    float4 y1 = h14[32 + part * 8 + q];
    c0 += w.x * y0.x + w.y * y0.y + w.z * y0.z + w.w * y0.w;
    c1 += w.x * y1.x + w.y * y1.y + w.z * y1.z + w.w * y1.w;
  }
  p2[part][0][h] = c0;
  p2[part][1][h] = c1;
  __syncthreads();
  if (tid < 256) {
    int r = tid >> 7, hh = tid & 127;
    float v = p2[0][r][hh] + p2[1][r][hh] + p2[2][r][hh] + p2[3][r][hh] + b2[hh];
    v = fmaxf(v, 0.f);
    prod[r][hh] = v * wo[NPAIRS + hh];
  }
  __syncthreads();

  if (tid < 128) {
    int r = tid >> 6, lane = tid & 63;
    float s = prod[r][lane] + prod[r][lane + 64];
    if (lane < 32) s += ws[WS_ACC + lane * 512 + b0 + r];  // fold fm partials
#pragma unroll
    for (int off = 32; off > 0; off >>= 1) s += __shfl_down(s, off, 64);
    if (lane == 0) out[b0 + r] = 1.f / (1.f + expf(-(s + bo[0])));
  }
}

extern "C" void kernel_launch(void* const* d_in, const int* in_sizes, int n_in,
                              void* d_out, int out_size, void* d_ws, size_t ws_size,
                              hipStream_t stream) {
  const float* x   = (const float*)d_in[0];
  const float* fmw = (const float*)d_in[1];
  const float* w1  = (const float*)d_in[2];
  const float* b1  = (const float*)d_in[3];
  const float* w2  = (const float*)d_in[4];
  const float* b2  = (const float*)d_in[5];
  const float* wo  = (const float*)d_in[6];
  const float* bo  = (const float*)d_in[7];
  float* out = (float*)d_out;
  float* ws  = (float*)d_ws;

  hipLaunchKernelGGL(k_build, dim3(1184), dim3(256), 0, stream, fmw, wo, w1, w2, ws);
  hipLaunchKernelGGL(k_fm,    dim3(2048), dim3(256), 0, stream, x, ws);
  hipLaunchKernelGGL(k_deep,  dim3(256),  dim3(512), 0, stream, x, b1, b2, wo, bo,
                     ws, out);
}